// Round 1
// baseline (650.597 us; speedup 1.0000x reference)
//
#include <hip/hip_runtime.h>
#include <hip/hip_bf16.h>

// Problem: N=32, T=2048, H=1024, D=384
//   h_proj = gru(N,T,H) @ W_h(H,H); energy = tanh(h_proj + c_proj + bias)
//   scores = energy . v ; weights = softmax_T(scores); context = sum_t w*gru
#define N_B 32
#define T_S 2048
#define H_D 1024
#define D_C 384
#define NT  (N_B * T_S)   // 65536

typedef __attribute__((ext_vector_type(8))) short bf16x8;
typedef __attribute__((ext_vector_type(4))) float f32x4;

__device__ __forceinline__ ushort f2bf(float f) {
    union { float f; unsigned u; } x; x.f = f;
    unsigned u = x.u;
    unsigned r = (u + 0x7FFFu + ((u >> 16) & 1u)) >> 16;  // RNE
    return (ushort)r;
}

__device__ __forceinline__ float fast_tanh(float x) {
    // tanh(x) = 1 - 2/(e^{2x}+1); stable: e->0 => -1, e->inf => +1
    float e = __expf(2.0f * x);
    return 1.0f - 2.0f / (e + 1.0f);
}

// ---------------- W_h (H,H) fp32 -> Wt (H,H) bf16 transposed: Wt[k][h] = W_h[h][k]
__global__ __launch_bounds__(256) void transpose_kernel(
    const float* __restrict__ W, ushort* __restrict__ Wt)
{
    __shared__ ushort tile[64 * 66];
    const int bx = blockIdx.x & 15;   // col tile of W
    const int by = blockIdx.x >> 4;   // row tile of W
    const int t = threadIdx.x;
    #pragma unroll
    for (int i = 0; i < 16; ++i) {
        int idx = t + i * 256;
        int r = idx >> 6, c = idx & 63;
        tile[r * 66 + c] = f2bf(W[(size_t)(by * 64 + r) * H_D + bx * 64 + c]);
    }
    __syncthreads();
    #pragma unroll
    for (int i = 0; i < 16; ++i) {
        int idx = t + i * 256;
        int r = idx >> 6, c = idx & 63;
        Wt[(size_t)(bx * 64 + r) * H_D + by * 64 + c] = tile[c * 66 + r];
    }
}

// ---------------- c_proj[n,k] = sum_d cond[n,d] * W_c[d,k] + bias[k]
__global__ __launch_bounds__(256) void cproj_kernel(
    const float* __restrict__ cond, const float* __restrict__ Wc,
    const float* __restrict__ bias, float* __restrict__ cproj)
{
    const int idx = blockIdx.x * 256 + threadIdx.x;  // 32768
    const int n = idx >> 10, k = idx & 1023;
    float acc = bias[k];
    const float* cp = cond + n * D_C;
    for (int d = 0; d < D_C; ++d)
        acc = fmaf(cp[d], Wc[(size_t)d * H_D + k], acc);
    cproj[idx] = acc;
}

// ---------------- fused GEMM (bf16 MFMA) + tanh + dot-v -> partial scores
// grid (kb=8, mb=512); 128x128 tile; 4 waves in 2x2, each 4x4 of 16x16x32 MFMA
#define LDSS 40  // shorts per LDS row: 80B = 16B-aligned, 2-way-free banks
__global__ __launch_bounds__(256) void gemm_score_kernel(
    const float* __restrict__ gru, const ushort* __restrict__ Wt,
    const float* __restrict__ cproj, const float* __restrict__ v,
    float* __restrict__ scores)
{
    __shared__ __align__(16) ushort As[128 * LDSS];
    __shared__ __align__(16) ushort Bt[128 * LDSS];
    const int kb = blockIdx.x;       // output-column block (0..7)
    const int mb = blockIdx.y;       // row block (0..511)
    const int m0 = mb * 128;
    const int nbatch = mb >> 4;      // 2048/128 = 16 m-blocks per n
    const int t = threadIdx.x;
    const int lane = t & 63, wave = t >> 6;
    const int wm = wave & 1, wn = wave >> 1;
    const int q = lane >> 4, ln = lane & 15;

    f32x4 acc[4][4];
    #pragma unroll
    for (int i = 0; i < 4; ++i)
        #pragma unroll
        for (int j = 0; j < 4; ++j)
            acc[i][j] = (f32x4){0.f, 0.f, 0.f, 0.f};

    for (int h0 = 0; h0 < H_D; h0 += 32) {
        if (h0) __syncthreads();
        // stage A: 128 rows x 32 h, fp32 -> bf16
        #pragma unroll
        for (int i = 0; i < 4; ++i) {
            int f = t + i * 256;               // 0..1023
            int row = f >> 3, c4 = f & 7;
            const float4 val = *(const float4*)(gru + (size_t)(m0 + row) * H_D + h0 + c4 * 4);
            ushort4 o;
            o.x = f2bf(val.x); o.y = f2bf(val.y); o.z = f2bf(val.z); o.w = f2bf(val.w);
            *(ushort4*)(&As[row * LDSS + c4 * 4]) = o;
        }
        // stage B^T: Bt[n][k] from pre-transposed bf16 Wt
        #pragma unroll
        for (int i = 0; i < 2; ++i) {
            int f = t + i * 256;               // 0..511
            int n = f >> 2, c = f & 3;
            uint4 wv = *(const uint4*)(Wt + (size_t)(kb * 128 + n) * H_D + h0 + c * 8);
            *(uint4*)(&Bt[n * LDSS + c * 8]) = wv;
        }
        __syncthreads();
        bf16x8 a[4], b[4];
        #pragma unroll
        for (int i = 0; i < 4; ++i)
            a[i] = *(const bf16x8*)(&As[(wm * 64 + i * 16 + ln) * LDSS + q * 8]);
        #pragma unroll
        for (int j = 0; j < 4; ++j)
            b[j] = *(const bf16x8*)(&Bt[(wn * 64 + j * 16 + ln) * LDSS + q * 8]);
        #pragma unroll
        for (int i = 0; i < 4; ++i)
            #pragma unroll
            for (int j = 0; j < 4; ++j)
                acc[i][j] = __builtin_amdgcn_mfma_f32_16x16x32_bf16(a[i], b[j], acc[i][j], 0, 0, 0);
    }

    // epilogue: e = tanh(C + cproj) * v ; reduce over this tile's 128 columns
    float cpv[4], vv[4];
    const float* cpn = cproj + nbatch * H_D;
    #pragma unroll
    for (int j = 0; j < 4; ++j) {
        int col = kb * 128 + wn * 64 + j * 16 + ln;
        cpv[j] = cpn[col];
        vv[j] = v[col];
    }
    #pragma unroll
    for (int i = 0; i < 4; ++i) {
        float s0 = 0.f, s1 = 0.f, s2 = 0.f, s3 = 0.f;
        #pragma unroll
        for (int j = 0; j < 4; ++j) {
            s0 += fast_tanh(acc[i][j][0] + cpv[j]) * vv[j];
            s1 += fast_tanh(acc[i][j][1] + cpv[j]) * vv[j];
            s2 += fast_tanh(acc[i][j][2] + cpv[j]) * vv[j];
            s3 += fast_tanh(acc[i][j][3] + cpv[j]) * vv[j];
        }
        // reduce across the 16 lanes holding different columns (same quad)
        #pragma unroll
        for (int off = 1; off < 16; off <<= 1) {
            s0 += __shfl_xor(s0, off);
            s1 += __shfl_xor(s1, off);
            s2 += __shfl_xor(s2, off);
            s3 += __shfl_xor(s3, off);
        }
        if (ln == 0) {
            int mrow = m0 + wm * 64 + i * 16 + q * 4;
            atomicAdd(&scores[mrow + 0], s0);
            atomicAdd(&scores[mrow + 1], s1);
            atomicAdd(&scores[mrow + 2], s2);
            atomicAdd(&scores[mrow + 3], s3);
        }
    }
}

// ---------------- softmax over T per n
__global__ __launch_bounds__(256) void softmax_kernel(
    const float* __restrict__ scores, float* __restrict__ weights)
{
    const int n = blockIdx.x;
    const int t = threadIdx.x;
    __shared__ float red[256];
    float sv[8];
    float m = -1e30f;
    #pragma unroll
    for (int i = 0; i < 8; ++i) {
        sv[i] = scores[n * T_S + i * 256 + t];
        m = fmaxf(m, sv[i]);
    }
    red[t] = m; __syncthreads();
    for (int s = 128; s > 0; s >>= 1) {
        if (t < s) red[t] = fmaxf(red[t], red[t + s]);
        __syncthreads();
    }
    const float mx = red[0];
    __syncthreads();
    float sum = 0.f;
    #pragma unroll
    for (int i = 0; i < 8; ++i) { sv[i] = __expf(sv[i] - mx); sum += sv[i]; }
    red[t] = sum; __syncthreads();
    for (int s = 128; s > 0; s >>= 1) {
        if (t < s) red[t] += red[t + s];
        __syncthreads();
    }
    const float inv = 1.0f / red[0];
    #pragma unroll
    for (int i = 0; i < 8; ++i) weights[n * T_S + i * 256 + t] = sv[i] * inv;
}

// ---------------- context[n,h] = sum_t weights[n,t] * gru[n,t,h]
__global__ __launch_bounds__(256) void context_kernel(
    const float* __restrict__ gru, const float* __restrict__ weights,
    float* __restrict__ out)
{
    const int tb = blockIdx.x;   // 0..7 (t blocks of 256)
    const int n  = blockIdx.y;   // 0..31
    const int t4 = threadIdx.x;  // h/4
    float4 acc = make_float4(0.f, 0.f, 0.f, 0.f);
    const float* wp = weights + n * T_S + tb * 256;
    const float* gp = gru + (size_t)(n * T_S + tb * 256) * H_D + t4 * 4;
    for (int tt = 0; tt < 256; ++tt) {
        float w = wp[tt];
        float4 gv = *(const float4*)(gp + (size_t)tt * H_D);
        acc.x += w * gv.x; acc.y += w * gv.y;
        acc.z += w * gv.z; acc.w += w * gv.w;
    }
    float* op = out + n * H_D + t4 * 4;
    atomicAdd(op + 0, acc.x);
    atomicAdd(op + 1, acc.y);
    atomicAdd(op + 2, acc.z);
    atomicAdd(op + 3, acc.w);
}

extern "C" void kernel_launch(void* const* d_in, const int* in_sizes, int n_in,
                              void* d_out, int out_size, void* d_ws, size_t ws_size,
                              hipStream_t stream)
{
    const float* gru  = (const float*)d_in[0];
    const float* cond = (const float*)d_in[1];
    const float* W_h  = (const float*)d_in[2];
    const float* W_c  = (const float*)d_in[3];
    const float* bias = (const float*)d_in[4];
    const float* v    = (const float*)d_in[5];
    float* out = (float*)d_out;

    char* ws = (char*)d_ws;
    ushort* Wt     = (ushort*)ws;                                   // 2 MiB
    float*  cproj  = (float*)(ws + (2u << 20));                     // 128 KiB
    float*  scores = (float*)(ws + (2u << 20) + (128u << 10));      // 256 KiB
    float*  wts    = (float*)(ws + (2u << 20) + (384u << 10));      // 256 KiB

    hipMemsetAsync(scores, 0, NT * sizeof(float), stream);
    hipMemsetAsync(out, 0, N_B * H_D * sizeof(float), stream);

    transpose_kernel<<<256, 256, 0, stream>>>(W_h, Wt);
    cproj_kernel<<<128, 256, 0, stream>>>(cond, W_c, bias, cproj);
    gemm_score_kernel<<<dim3(8, 512), 256, 0, stream>>>(gru, Wt, cproj, v, scores);
    softmax_kernel<<<N_B, 256, 0, stream>>>(scores, wts);
    context_kernel<<<dim3(8, N_B), 256, 0, stream>>>(gru, wts, out);
}

// Round 2
// 634.825 us; speedup vs baseline: 1.0248x; 1.0248x over previous
//
#include <hip/hip_runtime.h>
#include <hip/hip_bf16.h>

// Problem: N=32, T=2048, H=1024, D=384
//   h_proj = gru(N,T,H) @ W_h(H,H); energy = tanh(h_proj + c_proj + bias)
//   scores = energy . v ; weights = softmax_T(scores); context = sum_t w*gru
#define N_B 32
#define T_S 2048
#define H_D 1024
#define D_C 384
#define NT  (N_B * T_S)   // 65536

typedef __attribute__((ext_vector_type(8))) short bf16x8;
typedef __attribute__((ext_vector_type(4))) float f32x4;
typedef __attribute__((ext_vector_type(8))) unsigned short u16x8;

__device__ __forceinline__ ushort f2bf(float f) {
    union { float f; unsigned u; } x; x.f = f;
    unsigned u = x.u;
    unsigned r = (u + 0x7FFFu + ((u >> 16) & 1u)) >> 16;  // RNE
    return (ushort)r;
}

__device__ __forceinline__ float fast_tanh(float x) {
    float e = __expf(2.0f * x);
    return 1.0f - 2.0f / (e + 1.0f);
}

// async global->LDS, 16B per lane; LDS dest = wave-uniform base + lane*16
__device__ __forceinline__ void gl2lds16(const void* g, void* l) {
    __builtin_amdgcn_global_load_lds(
        (const __attribute__((address_space(1))) void*)g,
        (__attribute__((address_space(3))) void*)l, 16, 0, 0);
}

// ---------------- gru fp32 -> bf16 (one pass)
__global__ __launch_bounds__(256) void convert_kernel(
    const float* __restrict__ g, ushort* __restrict__ gb)
{
    const size_t base = ((size_t)blockIdx.x * 256 + threadIdx.x) * 8;
    float4 v0 = *(const float4*)(g + base);
    float4 v1 = *(const float4*)(g + base + 4);
    u16x8 o;
    o[0] = f2bf(v0.x); o[1] = f2bf(v0.y); o[2] = f2bf(v0.z); o[3] = f2bf(v0.w);
    o[4] = f2bf(v1.x); o[5] = f2bf(v1.y); o[6] = f2bf(v1.z); o[7] = f2bf(v1.w);
    *(u16x8*)(gb + base) = o;
}

// ---------------- W_h (H,H) fp32 -> Wt (H,H) bf16 transposed: Wt[k][h] = W_h[h][k]
__global__ __launch_bounds__(256) void transpose_kernel(
    const float* __restrict__ W, ushort* __restrict__ Wt)
{
    __shared__ ushort tile[64 * 66];
    const int bx = blockIdx.x & 15;
    const int by = blockIdx.x >> 4;
    const int t = threadIdx.x;
    #pragma unroll
    for (int i = 0; i < 16; ++i) {
        int idx = t + i * 256;
        int r = idx >> 6, c = idx & 63;
        tile[r * 66 + c] = f2bf(W[(size_t)(by * 64 + r) * H_D + bx * 64 + c]);
    }
    __syncthreads();
    #pragma unroll
    for (int i = 0; i < 16; ++i) {
        int idx = t + i * 256;
        int r = idx >> 6, c = idx & 63;
        Wt[(size_t)(bx * 64 + r) * H_D + by * 64 + c] = tile[c * 66 + r];
    }
}

// ---------------- c_proj[n,k] = sum_d cond[n,d] * W_c[d,k] + bias[k]
__global__ __launch_bounds__(256) void cproj_kernel(
    const float* __restrict__ cond, const float* __restrict__ Wc,
    const float* __restrict__ bias, float* __restrict__ cproj)
{
    const int idx = blockIdx.x * 256 + threadIdx.x;  // 32768
    const int n = idx >> 10, k = idx & 1023;
    float a0 = bias[k], a1 = 0.f, a2 = 0.f, a3 = 0.f;
    const float* cp = cond + n * D_C;
    for (int d = 0; d < D_C; d += 4) {
        a0 = fmaf(cp[d + 0], Wc[(size_t)(d + 0) * H_D + k], a0);
        a1 = fmaf(cp[d + 1], Wc[(size_t)(d + 1) * H_D + k], a1);
        a2 = fmaf(cp[d + 2], Wc[(size_t)(d + 2) * H_D + k], a2);
        a3 = fmaf(cp[d + 3], Wc[(size_t)(d + 3) * H_D + k], a3);
    }
    cproj[idx] = (a0 + a1) + (a2 + a3);
}

// ---------------- m97-style GEMM (bf16 A via global_load_lds) + tanh + dot-v
// grid (kb=8, mb=512); 128x128 tile; 4 waves 2x2, each 4x4 of 16x16x32 MFMA
// writes per-kb partial scores (no atomics)
__global__ __launch_bounds__(256) void gemm2_kernel(
    const ushort* __restrict__ Ab, const ushort* __restrict__ Wt,
    const float* __restrict__ cproj, const float* __restrict__ v,
    float* __restrict__ spart)
{
    __shared__ __align__(16) ushort As[128 * 32];   // 8 KiB, row-major, k-contig
    __shared__ __align__(16) ushort Bs[128 * 32];   // 8 KiB
    __shared__ float red[2][2][4][16];
    const int kb = blockIdx.x;
    const int mb = blockIdx.y;
    const int m0 = mb * 128;
    const int nbatch = mb >> 4;
    const int t = threadIdx.x;
    const int lane = t & 63, wave = t >> 6;
    const int wm = wave & 1, wn = wave >> 1;
    const int q = lane >> 4, ln = lane & 15;

    // staging source pointers: thread tt=c*256+t covers row tt>>2, k-part (tt&3)*8
    const ushort* ag0 = Ab + (size_t)(m0 + (t >> 2)) * H_D + (t & 3) * 8;
    const ushort* ag1 = Ab + (size_t)(m0 + 64 + (t >> 2)) * H_D + (t & 3) * 8;
    const ushort* bg0 = Wt + (size_t)(kb * 128 + (t >> 2)) * H_D + (t & 3) * 8;
    const ushort* bg1 = Wt + (size_t)(kb * 128 + 64 + (t >> 2)) * H_D + (t & 3) * 8;
    ushort* asd0 = As + wave * 512;            // bytes: wave*1024
    ushort* asd1 = As + 2048 + wave * 512;
    ushort* bsd0 = Bs + wave * 512;
    ushort* bsd1 = Bs + 2048 + wave * 512;

    f32x4 acc[4][4];
    #pragma unroll
    for (int i = 0; i < 4; ++i)
        #pragma unroll
        for (int j = 0; j < 4; ++j)
            acc[i][j] = (f32x4){0.f, 0.f, 0.f, 0.f};

    for (int h0 = 0; h0 < H_D; h0 += 32) {
        if (h0) __syncthreads();
        gl2lds16(ag0 + h0, asd0);
        gl2lds16(ag1 + h0, asd1);
        gl2lds16(bg0 + h0, bsd0);
        gl2lds16(bg1 + h0, bsd1);
        __syncthreads();   // compiler inserts vmcnt(0) drain before barrier
        bf16x8 a[4], b[4];
        #pragma unroll
        for (int i = 0; i < 4; ++i)
            a[i] = *(const bf16x8*)(&As[(wm * 64 + i * 16 + ln) * 32 + q * 8]);
        #pragma unroll
        for (int j = 0; j < 4; ++j)
            b[j] = *(const bf16x8*)(&Bs[(wn * 64 + j * 16 + ln) * 32 + q * 8]);
        #pragma unroll
        for (int i = 0; i < 4; ++i)
            #pragma unroll
            for (int j = 0; j < 4; ++j)
                acc[i][j] = __builtin_amdgcn_mfma_f32_16x16x32_bf16(a[i], b[j], acc[i][j], 0, 0, 0);
    }

    // epilogue: e = tanh(C + cproj) * v ; reduce over this tile's 128 columns
    float cpv[4], vv[4];
    const float* cpn = cproj + nbatch * H_D;
    #pragma unroll
    for (int j = 0; j < 4; ++j) {
        int col = kb * 128 + wn * 64 + j * 16 + ln;
        cpv[j] = cpn[col];
        vv[j] = v[col];
    }
    #pragma unroll
    for (int i = 0; i < 4; ++i) {
        float s0 = 0.f, s1 = 0.f, s2 = 0.f, s3 = 0.f;
        #pragma unroll
        for (int j = 0; j < 4; ++j) {
            s0 += fast_tanh(acc[i][j][0] + cpv[j]) * vv[j];
            s1 += fast_tanh(acc[i][j][1] + cpv[j]) * vv[j];
            s2 += fast_tanh(acc[i][j][2] + cpv[j]) * vv[j];
            s3 += fast_tanh(acc[i][j][3] + cpv[j]) * vv[j];
        }
        #pragma unroll
        for (int off = 1; off < 16; off <<= 1) {
            s0 += __shfl_xor(s0, off);
            s1 += __shfl_xor(s1, off);
            s2 += __shfl_xor(s2, off);
            s3 += __shfl_xor(s3, off);
        }
        if (ln == 0) {
            red[wm][wn][i][q * 4 + 0] = s0;
            red[wm][wn][i][q * 4 + 1] = s1;
            red[wm][wn][i][q * 4 + 2] = s2;
            red[wm][wn][i][q * 4 + 3] = s3;
        }
    }
    __syncthreads();
    if (t < 128) {
        int wm2 = t >> 6, idx = t & 63;
        int i2 = idx >> 4, qr = idx & 15;
        float val = red[wm2][0][i2][qr] + red[wm2][1][i2][qr];
        spart[(size_t)kb * NT + m0 + wm2 * 64 + idx] = val;
    }
}

// ---------------- legacy fused GEMM (fallback when ws too small)
#define LDSS 40
__global__ __launch_bounds__(256) void gemm_score_kernel(
    const float* __restrict__ gru, const ushort* __restrict__ Wt,
    const float* __restrict__ cproj, const float* __restrict__ v,
    float* __restrict__ scores)
{
    __shared__ __align__(16) ushort As[128 * LDSS];
    __shared__ __align__(16) ushort Bt[128 * LDSS];
    const int kb = blockIdx.x;
    const int mb = blockIdx.y;
    const int m0 = mb * 128;
    const int nbatch = mb >> 4;
    const int t = threadIdx.x;
    const int lane = t & 63, wave = t >> 6;
    const int wm = wave & 1, wn = wave >> 1;
    const int q = lane >> 4, ln = lane & 15;

    f32x4 acc[4][4];
    #pragma unroll
    for (int i = 0; i < 4; ++i)
        #pragma unroll
        for (int j = 0; j < 4; ++j)
            acc[i][j] = (f32x4){0.f, 0.f, 0.f, 0.f};

    for (int h0 = 0; h0 < H_D; h0 += 32) {
        if (h0) __syncthreads();
        #pragma unroll
        for (int i = 0; i < 4; ++i) {
            int f = t + i * 256;
            int row = f >> 3, c4 = f & 7;
            const float4 val = *(const float4*)(gru + (size_t)(m0 + row) * H_D + h0 + c4 * 4);
            ushort4 o;
            o.x = f2bf(val.x); o.y = f2bf(val.y); o.z = f2bf(val.z); o.w = f2bf(val.w);
            *(ushort4*)(&As[row * LDSS + c4 * 4]) = o;
        }
        #pragma unroll
        for (int i = 0; i < 2; ++i) {
            int f = t + i * 256;
            int n = f >> 2, c = f & 3;
            uint4 wv = *(const uint4*)(Wt + (size_t)(kb * 128 + n) * H_D + h0 + c * 8);
            *(uint4*)(&Bt[n * LDSS + c * 8]) = wv;
        }
        __syncthreads();
        bf16x8 a[4], b[4];
        #pragma unroll
        for (int i = 0; i < 4; ++i)
            a[i] = *(const bf16x8*)(&As[(wm * 64 + i * 16 + ln) * LDSS + q * 8]);
        #pragma unroll
        for (int j = 0; j < 4; ++j)
            b[j] = *(const bf16x8*)(&Bt[(wn * 64 + j * 16 + ln) * LDSS + q * 8]);
        #pragma unroll
        for (int i = 0; i < 4; ++i)
            #pragma unroll
            for (int j = 0; j < 4; ++j)
                acc[i][j] = __builtin_amdgcn_mfma_f32_16x16x32_bf16(a[i], b[j], acc[i][j], 0, 0, 0);
    }

    float cpv[4], vv[4];
    const float* cpn = cproj + nbatch * H_D;
    #pragma unroll
    for (int j = 0; j < 4; ++j) {
        int col = kb * 128 + wn * 64 + j * 16 + ln;
        cpv[j] = cpn[col];
        vv[j] = v[col];
    }
    #pragma unroll
    for (int i = 0; i < 4; ++i) {
        float s0 = 0.f, s1 = 0.f, s2 = 0.f, s3 = 0.f;
        #pragma unroll
        for (int j = 0; j < 4; ++j) {
            s0 += fast_tanh(acc[i][j][0] + cpv[j]) * vv[j];
            s1 += fast_tanh(acc[i][j][1] + cpv[j]) * vv[j];
            s2 += fast_tanh(acc[i][j][2] + cpv[j]) * vv[j];
            s3 += fast_tanh(acc[i][j][3] + cpv[j]) * vv[j];
        }
        #pragma unroll
        for (int off = 1; off < 16; off <<= 1) {
            s0 += __shfl_xor(s0, off);
            s1 += __shfl_xor(s1, off);
            s2 += __shfl_xor(s2, off);
            s3 += __shfl_xor(s3, off);
        }
        if (ln == 0) {
            int mrow = m0 + wm * 64 + i * 16 + q * 4;
            atomicAdd(&scores[mrow + 0], s0);
            atomicAdd(&scores[mrow + 1], s1);
            atomicAdd(&scores[mrow + 2], s2);
            atomicAdd(&scores[mrow + 3], s3);
        }
    }
}

// ---------------- softmax over T per n, summing 8 kb-partials
__global__ __launch_bounds__(256) void softmax8_kernel(
    const float* __restrict__ spart, float* __restrict__ weights)
{
    const int n = blockIdx.x;
    const int t = threadIdx.x;
    __shared__ float red[256];
    float sv[8];
    float m = -1e30f;
    #pragma unroll
    for (int i = 0; i < 8; ++i) {
        int mrow = n * T_S + i * 256 + t;
        float s = 0.f;
        #pragma unroll
        for (int kb = 0; kb < 8; ++kb) s += spart[(size_t)kb * NT + mrow];
        sv[i] = s;
        m = fmaxf(m, s);
    }
    red[t] = m; __syncthreads();
    for (int s = 128; s > 0; s >>= 1) {
        if (t < s) red[t] = fmaxf(red[t], red[t + s]);
        __syncthreads();
    }
    const float mx = red[0];
    __syncthreads();
    float sum = 0.f;
    #pragma unroll
    for (int i = 0; i < 8; ++i) { sv[i] = __expf(sv[i] - mx); sum += sv[i]; }
    red[t] = sum; __syncthreads();
    for (int s = 128; s > 0; s >>= 1) {
        if (t < s) red[t] += red[t + s];
        __syncthreads();
    }
    const float inv = 1.0f / red[0];
    #pragma unroll
    for (int i = 0; i < 8; ++i) weights[n * T_S + i * 256 + t] = sv[i] * inv;
}

// ---------------- plain softmax (fallback path)
__global__ __launch_bounds__(256) void softmax_kernel(
    const float* __restrict__ scores, float* __restrict__ weights)
{
    const int n = blockIdx.x;
    const int t = threadIdx.x;
    __shared__ float red[256];
    float sv[8];
    float m = -1e30f;
    #pragma unroll
    for (int i = 0; i < 8; ++i) {
        sv[i] = scores[n * T_S + i * 256 + t];
        m = fmaxf(m, sv[i]);
    }
    red[t] = m; __syncthreads();
    for (int s = 128; s > 0; s >>= 1) {
        if (t < s) red[t] = fmaxf(red[t], red[t + s]);
        __syncthreads();
    }
    const float mx = red[0];
    __syncthreads();
    float sum = 0.f;
    #pragma unroll
    for (int i = 0; i < 8; ++i) { sv[i] = __expf(sv[i] - mx); sum += sv[i]; }
    red[t] = sum; __syncthreads();
    for (int s = 128; s > 0; s >>= 1) {
        if (t < s) red[t] += red[t + s];
        __syncthreads();
    }
    const float inv = 1.0f / red[0];
    #pragma unroll
    for (int i = 0; i < 8; ++i) weights[n * T_S + i * 256 + t] = sv[i] * inv;
}

// ---------------- context[n,h] = sum_t weights[n,t] * gru[n,t,h]  (fp32 gru for accuracy)
__global__ __launch_bounds__(256) void context_kernel(
    const float* __restrict__ gru, const float* __restrict__ weights,
    float* __restrict__ out)
{
    const int tb = blockIdx.x;
    const int n  = blockIdx.y;
    const int t4 = threadIdx.x;
    float4 acc = make_float4(0.f, 0.f, 0.f, 0.f);
    const float* wp = weights + n * T_S + tb * 256;
    const float* gp = gru + (size_t)(n * T_S + tb * 256) * H_D + t4 * 4;
    for (int tt = 0; tt < 256; ++tt) {
        float w = wp[tt];
        float4 gv = *(const float4*)(gp + (size_t)tt * H_D);
        acc.x += w * gv.x; acc.y += w * gv.y;
        acc.z += w * gv.z; acc.w += w * gv.w;
    }
    float* op = out + n * H_D + t4 * 4;
    atomicAdd(op + 0, acc.x);
    atomicAdd(op + 1, acc.y);
    atomicAdd(op + 2, acc.z);
    atomicAdd(op + 3, acc.w);
}

extern "C" void kernel_launch(void* const* d_in, const int* in_sizes, int n_in,
                              void* d_out, int out_size, void* d_ws, size_t ws_size,
                              hipStream_t stream)
{
    const float* gru  = (const float*)d_in[0];
    const float* cond = (const float*)d_in[1];
    const float* W_h  = (const float*)d_in[2];
    const float* W_c  = (const float*)d_in[3];
    const float* bias = (const float*)d_in[4];
    const float* v    = (const float*)d_in[5];
    float* out = (float*)d_out;

    char* ws = (char*)d_ws;
    const size_t szAb    = (size_t)NT * H_D * 2;        // 128 MiB
    const size_t szWt    = (size_t)H_D * H_D * 2;       // 2 MiB
    const size_t szCproj = (size_t)N_B * H_D * 4;       // 128 KiB
    const size_t szSpart = (size_t)8 * NT * 4;          // 2 MiB
    const size_t szWts   = (size_t)NT * 4;              // 256 KiB
    const size_t need = szAb + szWt + szCproj + szSpart + szWts;

    if (ws_size >= need) {
        ushort* Ab    = (ushort*)ws;
        ushort* Wt    = (ushort*)(ws + szAb);
        float* cproj  = (float*)(ws + szAb + szWt);
        float* spart  = (float*)(ws + szAb + szWt + szCproj);
        float* wts    = (float*)(ws + szAb + szWt + szCproj + szSpart);

        hipMemsetAsync(out, 0, N_B * H_D * sizeof(float), stream);
        convert_kernel<<<32768, 256, 0, stream>>>(gru, Ab);
        transpose_kernel<<<256, 256, 0, stream>>>(W_h, Wt);
        cproj_kernel<<<128, 256, 0, stream>>>(cond, W_c, bias, cproj);
        gemm2_kernel<<<dim3(8, 512), 256, 0, stream>>>(Ab, Wt, cproj, v, spart);
        softmax8_kernel<<<N_B, 256, 0, stream>>>(spart, wts);
        context_kernel<<<dim3(8, N_B), 256, 0, stream>>>(gru, wts, out);
    } else {
        ushort* Wt    = (ushort*)ws;
        float* cproj  = (float*)(ws + szWt);
        float* scores = (float*)(ws + szWt + szCproj);
        float* wts    = (float*)(ws + szWt + szCproj + (size_t)NT * 4);

        hipMemsetAsync(scores, 0, NT * sizeof(float), stream);
        hipMemsetAsync(out, 0, N_B * H_D * sizeof(float), stream);
        transpose_kernel<<<256, 256, 0, stream>>>(W_h, Wt);
        cproj_kernel<<<128, 256, 0, stream>>>(cond, W_c, bias, cproj);
        gemm_score_kernel<<<dim3(8, 512), 256, 0, stream>>>(gru, Wt, cproj, v, scores);
        softmax_kernel<<<N_B, 256, 0, stream>>>(scores, wts);
        context_kernel<<<dim3(8, N_B), 256, 0, stream>>>(gru, wts, out);
    }
}

// Round 3
// 581.177 us; speedup vs baseline: 1.1194x; 1.0923x over previous
//
#include <hip/hip_runtime.h>
#include <hip/hip_bf16.h>

// Problem: N=32, T=2048, H=1024, D=384
//   h_proj = gru(N,T,H) @ W_h(H,H); energy = tanh(h_proj + c_proj + bias)
//   scores = energy . v ; weights = softmax_T(scores); context = sum_t w*gru
#define N_B 32
#define T_S 2048
#define H_D 1024
#define D_C 384
#define NT  (N_B * T_S)   // 65536

typedef __attribute__((ext_vector_type(8))) short bf16x8;
typedef __attribute__((ext_vector_type(4))) float f32x4;
typedef __attribute__((ext_vector_type(8))) unsigned short u16x8;

__device__ __forceinline__ ushort f2bf(float f) {
    union { float f; unsigned u; } x; x.f = f;
    unsigned u = x.u;
    unsigned r = (u + 0x7FFFu + ((u >> 16) & 1u)) >> 16;  // RNE
    return (ushort)r;
}

__device__ __forceinline__ float bf2f(ushort u) {
    union { unsigned u; float f; } x; x.u = ((unsigned)u) << 16;
    return x.f;
}

__device__ __forceinline__ float fast_tanh(float x) {
    float e = __expf(2.0f * x);
    return 1.0f - 2.0f / (e + 1.0f);
}

// async global->LDS, 16B per lane; LDS dest = wave-uniform base + lane*16
__device__ __forceinline__ void gl2lds16(const void* g, void* l) {
    __builtin_amdgcn_global_load_lds(
        (const __attribute__((address_space(1))) void*)g,
        (__attribute__((address_space(3))) void*)l, 16, 0, 0);
}

// ---------------- gru fp32 -> bf16 (one pass)
__global__ __launch_bounds__(256) void convert_kernel(
    const float* __restrict__ g, ushort* __restrict__ gb)
{
    const size_t base = ((size_t)blockIdx.x * 256 + threadIdx.x) * 8;
    float4 v0 = *(const float4*)(g + base);
    float4 v1 = *(const float4*)(g + base + 4);
    u16x8 o;
    o[0] = f2bf(v0.x); o[1] = f2bf(v0.y); o[2] = f2bf(v0.z); o[3] = f2bf(v0.w);
    o[4] = f2bf(v1.x); o[5] = f2bf(v1.y); o[6] = f2bf(v1.z); o[7] = f2bf(v1.w);
    *(u16x8*)(gb + base) = o;
}

// ---------------- W_h (H,H) fp32 -> Wt (H,H) bf16 transposed: Wt[k][h] = W_h[h][k]
__global__ __launch_bounds__(256) void transpose_kernel(
    const float* __restrict__ W, ushort* __restrict__ Wt)
{
    __shared__ ushort tile[64 * 66];
    const int bx = blockIdx.x & 15;
    const int by = blockIdx.x >> 4;
    const int t = threadIdx.x;
    #pragma unroll
    for (int i = 0; i < 16; ++i) {
        int idx = t + i * 256;
        int r = idx >> 6, c = idx & 63;
        tile[r * 66 + c] = f2bf(W[(size_t)(by * 64 + r) * H_D + bx * 64 + c]);
    }
    __syncthreads();
    #pragma unroll
    for (int i = 0; i < 16; ++i) {
        int idx = t + i * 256;
        int r = idx >> 6, c = idx & 63;
        Wt[(size_t)(bx * 64 + r) * H_D + by * 64 + c] = tile[c * 66 + r];
    }
}

// ---------------- c_proj[n,k] = sum_d cond[n,d] * W_c[d,k] + bias[k]
__global__ __launch_bounds__(256) void cproj_kernel(
    const float* __restrict__ cond, const float* __restrict__ Wc,
    const float* __restrict__ bias, float* __restrict__ cproj)
{
    const int idx = blockIdx.x * 256 + threadIdx.x;  // 32768
    const int n = idx >> 10, k = idx & 1023;
    float a0 = bias[k], a1 = 0.f, a2 = 0.f, a3 = 0.f;
    const float* cp = cond + n * D_C;
    for (int d = 0; d < D_C; d += 4) {
        a0 = fmaf(cp[d + 0], Wc[(size_t)(d + 0) * H_D + k], a0);
        a1 = fmaf(cp[d + 1], Wc[(size_t)(d + 1) * H_D + k], a1);
        a2 = fmaf(cp[d + 2], Wc[(size_t)(d + 2) * H_D + k], a2);
        a3 = fmaf(cp[d + 3], Wc[(size_t)(d + 3) * H_D + k], a3);
    }
    cproj[idx] = (a0 + a1) + (a2 + a3);
}

// ---------------- GEMM + tanh + dot-v -> per-kb partial scores
// 1D grid 4096, XCD swizzle: the 8 kb-blocks of an mb are consecutive slots
// on ONE XCD so the A m-tile is fetched into that XCD's L2 once.
// 128x128 tile, BK=64, 4 waves 2x2, each 4x4 of 16x16x32 MFMA.
// LDS via global_load_lds with XOR k-chunk swizzle (kc = (l&7)^(l>>3)):
// frag reads then hit all 32 banks at 2 lanes/bank (free).
__global__ __launch_bounds__(256) void gemm3_kernel(
    const ushort* __restrict__ Ab, const ushort* __restrict__ Wt,
    const float* __restrict__ cproj, const float* __restrict__ v,
    float* __restrict__ spart)
{
    __shared__ __align__(16) ushort As[128 * 64];   // 16 KiB
    __shared__ __align__(16) ushort Bs[128 * 64];   // 16 KiB
    __shared__ float red[2][2][4][16];
    const int id = blockIdx.x;
    const int mb = (id & 7) + ((id >> 6) << 3);   // XCD = id%8 = mb%8
    const int kb = (id >> 3) & 7;
    const int m0 = mb * 128;
    const int nbatch = mb >> 4;
    const int t = threadIdx.x;
    const int lane = t & 63, wave = t >> 6;
    const int wm = wave & 1, wn = wave >> 1;
    const int q = lane >> 4, ln = lane & 15;
    const int x7 = ln & 7;                        // row&7 for frag rows

    // staging: issue i covers rows i*32..i*32+31; wave w lanes l ->
    //   row = i*32 + w*8 + (l>>3), k-chunk kc = (l&7)^(l>>3) (XOR swizzle)
    const int srow = wave * 8 + (lane >> 3);
    const int koff = ((lane & 7) ^ (lane >> 3)) * 8;
    const ushort* ag = Ab + (size_t)(m0 + srow) * H_D + koff;
    const ushort* bg = Wt + (size_t)(kb * 128 + srow) * H_D + koff;

    f32x4 acc[4][4];
    #pragma unroll
    for (int i = 0; i < 4; ++i)
        #pragma unroll
        for (int j = 0; j < 4; ++j)
            acc[i][j] = (f32x4){0.f, 0.f, 0.f, 0.f};

    for (int h0 = 0; h0 < H_D; h0 += 64) {
        if (h0) __syncthreads();
        #pragma unroll
        for (int i = 0; i < 4; ++i) {
            gl2lds16(ag + h0 + i * 32 * H_D, As + i * 2048 + wave * 512);
            gl2lds16(bg + h0 + i * 32 * H_D, Bs + i * 2048 + wave * 512);
        }
        __syncthreads();
        #pragma unroll
        for (int kk = 0; kk < 2; ++kk) {
            bf16x8 a[4], b[4];
            #pragma unroll
            for (int i = 0; i < 4; ++i) {
                int row = wm * 64 + i * 16 + ln;
                a[i] = *(const bf16x8*)(&As[row * 64 + (((kk << 2) + q) ^ x7) * 8]);
            }
            #pragma unroll
            for (int j = 0; j < 4; ++j) {
                int row = wn * 64 + j * 16 + ln;
                b[j] = *(const bf16x8*)(&Bs[row * 64 + (((kk << 2) + q) ^ x7) * 8]);
            }
            #pragma unroll
            for (int i = 0; i < 4; ++i)
                #pragma unroll
                for (int j = 0; j < 4; ++j)
                    acc[i][j] = __builtin_amdgcn_mfma_f32_16x16x32_bf16(a[i], b[j], acc[i][j], 0, 0, 0);
        }
    }

    // epilogue: e = tanh(C + cproj) * v ; reduce over this tile's 128 columns
    float cpv[4], vv[4];
    const float* cpn = cproj + nbatch * H_D;
    #pragma unroll
    for (int j = 0; j < 4; ++j) {
        int col = kb * 128 + wn * 64 + j * 16 + ln;
        cpv[j] = cpn[col];
        vv[j] = v[col];
    }
    #pragma unroll
    for (int i = 0; i < 4; ++i) {
        float s0 = 0.f, s1 = 0.f, s2 = 0.f, s3 = 0.f;
        #pragma unroll
        for (int j = 0; j < 4; ++j) {
            s0 += fast_tanh(acc[i][j][0] + cpv[j]) * vv[j];
            s1 += fast_tanh(acc[i][j][1] + cpv[j]) * vv[j];
            s2 += fast_tanh(acc[i][j][2] + cpv[j]) * vv[j];
            s3 += fast_tanh(acc[i][j][3] + cpv[j]) * vv[j];
        }
        #pragma unroll
        for (int off = 1; off < 16; off <<= 1) {
            s0 += __shfl_xor(s0, off);
            s1 += __shfl_xor(s1, off);
            s2 += __shfl_xor(s2, off);
            s3 += __shfl_xor(s3, off);
        }
        if (ln == 0) {
            red[wm][wn][i][q * 4 + 0] = s0;
            red[wm][wn][i][q * 4 + 1] = s1;
            red[wm][wn][i][q * 4 + 2] = s2;
            red[wm][wn][i][q * 4 + 3] = s3;
        }
    }
    __syncthreads();
    if (t < 128) {
        int wm2 = t >> 6, idx = t & 63;
        int i2 = idx >> 4, qr = idx & 15;
        float val = red[wm2][0][i2][qr] + red[wm2][1][i2][qr];
        spart[(size_t)kb * NT + m0 + wm2 * 64 + idx] = val;
    }
}

// ---------------- softmax over T per n, summing 8 kb-partials
__global__ __launch_bounds__(256) void softmax8_kernel(
    const float* __restrict__ spart, float* __restrict__ weights)
{
    const int n = blockIdx.x;
    const int t = threadIdx.x;
    __shared__ float red[256];
    float sv[8];
    float m = -1e30f;
    #pragma unroll
    for (int i = 0; i < 8; ++i) {
        int mrow = n * T_S + i * 256 + t;
        float s = 0.f;
        #pragma unroll
        for (int kb = 0; kb < 8; ++kb) s += spart[(size_t)kb * NT + mrow];
        sv[i] = s;
        m = fmaxf(m, s);
    }
    red[t] = m; __syncthreads();
    for (int s = 128; s > 0; s >>= 1) {
        if (t < s) red[t] = fmaxf(red[t], red[t + s]);
        __syncthreads();
    }
    const float mx = red[0];
    __syncthreads();
    float sum = 0.f;
    #pragma unroll
    for (int i = 0; i < 8; ++i) { sv[i] = __expf(sv[i] - mx); sum += sv[i]; }
    red[t] = sum; __syncthreads();
    for (int s = 128; s > 0; s >>= 1) {
        if (t < s) red[t] += red[t + s];
        __syncthreads();
    }
    const float inv = 1.0f / red[0];
    #pragma unroll
    for (int i = 0; i < 8; ++i) weights[n * T_S + i * 256 + t] = sv[i] * inv;
}

// ---------------- context[n,h] = sum_t weights[n,t] * gru[n,t,h]  (bf16 gru)
// grid (32 t-slices, 32 n) = 1024 blocks; each thread: 4 h over 64 t's.
__global__ __launch_bounds__(256) void context2_kernel(
    const ushort* __restrict__ Ab, const float* __restrict__ weights,
    float* __restrict__ out)
{
    const int tb = blockIdx.x;   // 0..31, 64 t each
    const int n  = blockIdx.y;   // 0..31
    const int t  = threadIdx.x;  // h-chunk: 4 h (8 B)
    float a0 = 0.f, a1 = 0.f, a2 = 0.f, a3 = 0.f;
    const float* wp = weights + n * T_S + tb * 64;
    const ushort* gp = Ab + (size_t)(n * T_S + tb * 64) * H_D + t * 4;
    #pragma unroll 8
    for (int tt = 0; tt < 64; ++tt) {
        float w = wp[tt];
        ushort4 gv = *(const ushort4*)(gp + (size_t)tt * H_D);
        a0 = fmaf(w, bf2f(gv.x), a0);
        a1 = fmaf(w, bf2f(gv.y), a1);
        a2 = fmaf(w, bf2f(gv.z), a2);
        a3 = fmaf(w, bf2f(gv.w), a3);
    }
    float* op = out + n * H_D + t * 4;
    atomicAdd(op + 0, a0);
    atomicAdd(op + 1, a1);
    atomicAdd(op + 2, a2);
    atomicAdd(op + 3, a3);
}

extern "C" void kernel_launch(void* const* d_in, const int* in_sizes, int n_in,
                              void* d_out, int out_size, void* d_ws, size_t ws_size,
                              hipStream_t stream)
{
    const float* gru  = (const float*)d_in[0];
    const float* cond = (const float*)d_in[1];
    const float* W_h  = (const float*)d_in[2];
    const float* W_c  = (const float*)d_in[3];
    const float* bias = (const float*)d_in[4];
    const float* v    = (const float*)d_in[5];
    float* out = (float*)d_out;

    char* ws = (char*)d_ws;
    const size_t szAb    = (size_t)NT * H_D * 2;        // 128 MiB
    const size_t szWt    = (size_t)H_D * H_D * 2;       // 2 MiB
    const size_t szCproj = (size_t)N_B * H_D * 4;       // 128 KiB
    const size_t szSpart = (size_t)8 * NT * 4;          // 2 MiB

    ushort* Ab    = (ushort*)ws;
    ushort* Wt    = (ushort*)(ws + szAb);
    float* cproj  = (float*)(ws + szAb + szWt);
    float* spart  = (float*)(ws + szAb + szWt + szCproj);
    float* wts    = (float*)(ws + szAb + szWt + szCproj + szSpart);

    hipMemsetAsync(out, 0, N_B * H_D * sizeof(float), stream);
    convert_kernel<<<32768, 256, 0, stream>>>(gru, Ab);
    transpose_kernel<<<256, 256, 0, stream>>>(W_h, Wt);
    cproj_kernel<<<128, 256, 0, stream>>>(cond, W_c, bias, cproj);
    gemm3_kernel<<<4096, 256, 0, stream>>>(Ab, Wt, cproj, v, spart);
    softmax8_kernel<<<N_B, 256, 0, stream>>>(spart, wts);
    context2_kernel<<<dim3(32, N_B), 256, 0, stream>>>(Ab, wts, out);
}

// Round 4
// 560.912 us; speedup vs baseline: 1.1599x; 1.0361x over previous
//
#include <hip/hip_runtime.h>
#include <hip/hip_bf16.h>

// Problem: N=32, T=2048, H=1024, D=384
//   h_proj = gru(N,T,H) @ W_h(H,H); energy = tanh(h_proj + c_proj + bias)
//   scores = energy . v ; weights = softmax_T(scores); context = sum_t w*gru
#define N_B 32
#define T_S 2048
#define H_D 1024
#define D_C 384
#define NT  (N_B * T_S)   // 65536

typedef __attribute__((ext_vector_type(8))) short bf16x8;
typedef __attribute__((ext_vector_type(4))) float f32x4;

__device__ __forceinline__ ushort f2bf(float f) {
    union { float f; unsigned u; } x; x.f = f;
    unsigned u = x.u;
    unsigned r = (u + 0x7FFFu + ((u >> 16) & 1u)) >> 16;  // RNE
    return (ushort)r;
}

__device__ __forceinline__ float bf2f(ushort u) {
    union { unsigned u; float f; } x; x.u = ((unsigned)u) << 16;
    return x.f;
}

__device__ __forceinline__ float fast_tanh(float x) {
    float e = __expf(2.0f * x);
    return 1.0f - 2.0f / (e + 1.0f);
}

// async global->LDS, 16B per lane; LDS dest = wave-uniform base + lane*16
__device__ __forceinline__ void gl2lds16(const void* g, void* l) {
    __builtin_amdgcn_global_load_lds(
        (const __attribute__((address_space(1))) void*)g,
        (__attribute__((address_space(3))) void*)l, 16, 0, 0);
}

// ---------------- gru fp32 -> bf16, fully lane-contiguous (16B load / 8B store)
__global__ __launch_bounds__(256) void convert_kernel(
    const float* __restrict__ g, ushort* __restrict__ gb)
{
    const size_t base = ((size_t)blockIdx.x * 256 + threadIdx.x) * 4;
    float4 v = *(const float4*)(g + base);
    ushort4 o;
    o.x = f2bf(v.x); o.y = f2bf(v.y); o.z = f2bf(v.z); o.w = f2bf(v.w);
    *(ushort4*)(gb + base) = o;
}

// ---------------- W_h (H,H) fp32 -> Wt (H,H) bf16 transposed: Wt[k][h] = W_h[h][k]
__global__ __launch_bounds__(256) void transpose_kernel(
    const float* __restrict__ W, ushort* __restrict__ Wt)
{
    __shared__ ushort tile[64 * 66];
    const int bx = blockIdx.x & 15;
    const int by = blockIdx.x >> 4;
    const int t = threadIdx.x;
    #pragma unroll
    for (int i = 0; i < 16; ++i) {
        int idx = t + i * 256;
        int r = idx >> 6, c = idx & 63;
        tile[r * 66 + c] = f2bf(W[(size_t)(by * 64 + r) * H_D + bx * 64 + c]);
    }
    __syncthreads();
    #pragma unroll
    for (int i = 0; i < 16; ++i) {
        int idx = t + i * 256;
        int r = idx >> 6, c = idx & 63;
        Wt[(size_t)(bx * 64 + r) * H_D + by * 64 + c] = tile[c * 66 + r];
    }
}

// ---------------- c_proj[n,k] += sum_{d in slice} cond[n,d]*W_c[d,k] (+bias)
// d split 4 ways (96 each) for occupancy; cproj must be zeroed beforehand.
__global__ __launch_bounds__(256) void cproj_kernel(
    const float* __restrict__ cond, const float* __restrict__ Wc,
    const float* __restrict__ bias, float* __restrict__ cproj)
{
    const int idx = blockIdx.x * 256 + threadIdx.x;  // 32768
    const int n = idx >> 10, k = idx & 1023;
    const int d0 = blockIdx.y * 96;
    float a0 = (blockIdx.y == 0) ? bias[k] : 0.f;
    float a1 = 0.f, a2 = 0.f, a3 = 0.f;
    const float* cp = cond + n * D_C;
    for (int d = d0; d < d0 + 96; d += 4) {
        a0 = fmaf(cp[d + 0], Wc[(size_t)(d + 0) * H_D + k], a0);
        a1 = fmaf(cp[d + 1], Wc[(size_t)(d + 1) * H_D + k], a1);
        a2 = fmaf(cp[d + 2], Wc[(size_t)(d + 2) * H_D + k], a2);
        a3 = fmaf(cp[d + 3], Wc[(size_t)(d + 3) * H_D + k], a3);
    }
    atomicAdd(&cproj[idx], (a0 + a1) + (a2 + a3));
}

// ---------------- GEMM + tanh + dot-v -> per-kb partial scores (unchanged)
__global__ __launch_bounds__(256) void gemm3_kernel(
    const ushort* __restrict__ Ab, const ushort* __restrict__ Wt,
    const float* __restrict__ cproj, const float* __restrict__ v,
    float* __restrict__ spart)
{
    __shared__ __align__(16) ushort As[128 * 64];   // 16 KiB
    __shared__ __align__(16) ushort Bs[128 * 64];   // 16 KiB
    __shared__ float red[2][2][4][16];
    const int id = blockIdx.x;
    const int mb = (id & 7) + ((id >> 6) << 3);   // XCD = id%8 = mb%8
    const int kb = (id >> 3) & 7;
    const int m0 = mb * 128;
    const int nbatch = mb >> 4;
    const int t = threadIdx.x;
    const int lane = t & 63, wave = t >> 6;
    const int wm = wave & 1, wn = wave >> 1;
    const int q = lane >> 4, ln = lane & 15;
    const int x7 = ln & 7;

    const int srow = wave * 8 + (lane >> 3);
    const int koff = ((lane & 7) ^ (lane >> 3)) * 8;
    const ushort* ag = Ab + (size_t)(m0 + srow) * H_D + koff;
    const ushort* bg = Wt + (size_t)(kb * 128 + srow) * H_D + koff;

    f32x4 acc[4][4];
    #pragma unroll
    for (int i = 0; i < 4; ++i)
        #pragma unroll
        for (int j = 0; j < 4; ++j)
            acc[i][j] = (f32x4){0.f, 0.f, 0.f, 0.f};

    for (int h0 = 0; h0 < H_D; h0 += 64) {
        if (h0) __syncthreads();
        #pragma unroll
        for (int i = 0; i < 4; ++i) {
            gl2lds16(ag + h0 + i * 32 * H_D, As + i * 2048 + wave * 512);
            gl2lds16(bg + h0 + i * 32 * H_D, Bs + i * 2048 + wave * 512);
        }
        __syncthreads();
        #pragma unroll
        for (int kk = 0; kk < 2; ++kk) {
            bf16x8 a[4], b[4];
            #pragma unroll
            for (int i = 0; i < 4; ++i) {
                int row = wm * 64 + i * 16 + ln;
                a[i] = *(const bf16x8*)(&As[row * 64 + (((kk << 2) + q) ^ x7) * 8]);
            }
            #pragma unroll
            for (int j = 0; j < 4; ++j) {
                int row = wn * 64 + j * 16 + ln;
                b[j] = *(const bf16x8*)(&Bs[row * 64 + (((kk << 2) + q) ^ x7) * 8]);
            }
            #pragma unroll
            for (int i = 0; i < 4; ++i)
                #pragma unroll
                for (int j = 0; j < 4; ++j)
                    acc[i][j] = __builtin_amdgcn_mfma_f32_16x16x32_bf16(a[i], b[j], acc[i][j], 0, 0, 0);
        }
    }

    float cpv[4], vv[4];
    const float* cpn = cproj + nbatch * H_D;
    #pragma unroll
    for (int j = 0; j < 4; ++j) {
        int col = kb * 128 + wn * 64 + j * 16 + ln;
        cpv[j] = cpn[col];
        vv[j] = v[col];
    }
    #pragma unroll
    for (int i = 0; i < 4; ++i) {
        float s0 = 0.f, s1 = 0.f, s2 = 0.f, s3 = 0.f;
        #pragma unroll
        for (int j = 0; j < 4; ++j) {
            s0 += fast_tanh(acc[i][j][0] + cpv[j]) * vv[j];
            s1 += fast_tanh(acc[i][j][1] + cpv[j]) * vv[j];
            s2 += fast_tanh(acc[i][j][2] + cpv[j]) * vv[j];
            s3 += fast_tanh(acc[i][j][3] + cpv[j]) * vv[j];
        }
        #pragma unroll
        for (int off = 1; off < 16; off <<= 1) {
            s0 += __shfl_xor(s0, off);
            s1 += __shfl_xor(s1, off);
            s2 += __shfl_xor(s2, off);
            s3 += __shfl_xor(s3, off);
        }
        if (ln == 0) {
            red[wm][wn][i][q * 4 + 0] = s0;
            red[wm][wn][i][q * 4 + 1] = s1;
            red[wm][wn][i][q * 4 + 2] = s2;
            red[wm][wn][i][q * 4 + 3] = s3;
        }
    }
    __syncthreads();
    if (t < 128) {
        int wm2 = t >> 6, idx = t & 63;
        int i2 = idx >> 4, qr = idx & 15;
        float val = red[wm2][0][i2][qr] + red[wm2][1][i2][qr];
        spart[(size_t)kb * NT + m0 + wm2 * 64 + idx] = val;
    }
}

// ---------------- softmax over T per n, summing 8 kb-partials; 1024 threads
__global__ __launch_bounds__(1024) void softmax8_kernel(
    const float* __restrict__ spart, float* __restrict__ weights)
{
    const int n = blockIdx.x;
    const int t = threadIdx.x;   // 0..1023
    __shared__ float red[1024];
    float s0 = 0.f, s1 = 0.f;
    #pragma unroll
    for (int kb = 0; kb < 8; ++kb) {
        s0 += spart[(size_t)kb * NT + n * T_S + t];
        s1 += spart[(size_t)kb * NT + n * T_S + 1024 + t];
    }
    red[t] = fmaxf(s0, s1); __syncthreads();
    for (int s = 512; s > 0; s >>= 1) {
        if (t < s) red[t] = fmaxf(red[t], red[t + s]);
        __syncthreads();
    }
    const float mx = red[0];
    __syncthreads();
    float e0 = __expf(s0 - mx), e1 = __expf(s1 - mx);
    red[t] = e0 + e1; __syncthreads();
    for (int s = 512; s > 0; s >>= 1) {
        if (t < s) red[t] += red[t + s];
        __syncthreads();
    }
    const float inv = 1.0f / red[0];
    weights[n * T_S + t] = e0 * inv;
    weights[n * T_S + 1024 + t] = e1 * inv;
}

// ---------------- context partials: cpart[tb][n][h] = sum_{t in slice} w*gru
// tb = 16 slices of 128 t; no atomics.
__global__ __launch_bounds__(256) void context3_kernel(
    const ushort* __restrict__ Ab, const float* __restrict__ weights,
    float* __restrict__ cpart)
{
    const int tb = blockIdx.x;   // 0..15, 128 t each
    const int n  = blockIdx.y;   // 0..31
    const int t  = threadIdx.x;  // h-chunk: 4 h (8 B)
    float a0 = 0.f, a1 = 0.f, a2 = 0.f, a3 = 0.f;
    const float* wp = weights + n * T_S + tb * 128;
    const ushort* gp = Ab + (size_t)(n * T_S + tb * 128) * H_D + t * 4;
    #pragma unroll 8
    for (int tt = 0; tt < 128; ++tt) {
        float w = wp[tt];
        ushort4 gv = *(const ushort4*)(gp + (size_t)tt * H_D);
        a0 = fmaf(w, bf2f(gv.x), a0);
        a1 = fmaf(w, bf2f(gv.y), a1);
        a2 = fmaf(w, bf2f(gv.z), a2);
        a3 = fmaf(w, bf2f(gv.w), a3);
    }
    *(float4*)(cpart + ((size_t)tb * N_B + n) * H_D + t * 4) =
        make_float4(a0, a1, a2, a3);
}

// ---------------- out[n][h] = sum_tb cpart[tb][n][h]
__global__ __launch_bounds__(256) void reduce_kernel(
    const float* __restrict__ cpart, float* __restrict__ out)
{
    const int idx = blockIdx.x * 256 + threadIdx.x;  // 32768
    float s = 0.f;
    #pragma unroll
    for (int tb = 0; tb < 16; ++tb)
        s += cpart[(size_t)tb * (N_B * H_D) + idx];
    out[idx] = s;
}

extern "C" void kernel_launch(void* const* d_in, const int* in_sizes, int n_in,
                              void* d_out, int out_size, void* d_ws, size_t ws_size,
                              hipStream_t stream)
{
    const float* gru  = (const float*)d_in[0];
    const float* cond = (const float*)d_in[1];
    const float* W_h  = (const float*)d_in[2];
    const float* W_c  = (const float*)d_in[3];
    const float* bias = (const float*)d_in[4];
    const float* v    = (const float*)d_in[5];
    float* out = (float*)d_out;

    char* ws = (char*)d_ws;
    const size_t szAb    = (size_t)NT * H_D * 2;        // 128 MiB
    const size_t szWt    = (size_t)H_D * H_D * 2;       // 2 MiB
    const size_t szCproj = (size_t)N_B * H_D * 4;       // 128 KiB
    const size_t szSpart = (size_t)8 * NT * 4;          // 2 MiB

    ushort* Ab    = (ushort*)ws;
    ushort* Wt    = (ushort*)(ws + szAb);
    float* cproj  = (float*)(ws + szAb + szWt);
    float* spart  = (float*)(ws + szAb + szWt + szCproj);
    float* cpart  = spart;   // reuse: spart dead after softmax; same 2 MiB
    float* wts    = (float*)(ws + szAb + szWt + szCproj + szSpart);

    hipMemsetAsync(cproj, 0, szCproj, stream);
    convert_kernel<<<65536, 256, 0, stream>>>(gru, Ab);
    transpose_kernel<<<256, 256, 0, stream>>>(W_h, Wt);
    cproj_kernel<<<dim3(128, 4), 256, 0, stream>>>(cond, W_c, bias, cproj);
    gemm3_kernel<<<4096, 256, 0, stream>>>(Ab, Wt, cproj, v, spart);
    softmax8_kernel<<<N_B, 1024, 0, stream>>>(spart, wts);
    context3_kernel<<<dim3(16, N_B), 256, 0, stream>>>(Ab, wts, cpart);
    reduce_kernel<<<128, 256, 0, stream>>>(cpart, out);
}